// Round 13
// baseline (196.080 us; speedup 1.0000x reference)
//
#include <hip/hip_runtime.h>
#include <cstdint>
#include <cstddef>

#define N 1024
#define HN 4
#define FDIM 64
#define KSEL 512
#define FLT_MAX_ 3.402823466e+38f

// ---------------- reduction helpers ----------------
__device__ __forceinline__ float wred_sum(float v){
#pragma unroll
  for(int o=32;o>0;o>>=1) v += __shfl_down(v,o,64);
  return v;
}
__device__ __forceinline__ float bfly_sum(float v){
#pragma unroll
  for(int o=1;o<64;o<<=1) v += __shfl_xor(v,o,64);
  return v;
}
__device__ __forceinline__ float bfly_max(float v){
#pragma unroll
  for(int o=1;o<64;o<<=1) v = fmaxf(v,__shfl_xor(v,o,64));
  return v;
}
__device__ __forceinline__ int bfly_sumi(int v){
#pragma unroll
  for(int o=1;o<64;o<<=1) v += __shfl_xor(v,o,64);
  return v;
}
__device__ __forceinline__ float bred_sum(float v, float* scr){
  int t=threadIdx.x;
  v = wred_sum(v);
  __syncthreads();
  if((t&63)==0) scr[t>>6]=v;
  __syncthreads();
  return (scr[0]+scr[1])+(scr[2]+scr[3]);
}

// ---------------- K1: fused gemm + pack_adj + mask zero + feats min/max ----------
__global__ __launch_bounds__(256) void stage1(const float* __restrict__ x,
                                              const float* __restrict__ W_l,
                                              const float* __restrict__ W_r,
                                              const int* __restrict__ adj,
                                              const float* __restrict__ feats,
                                              float* __restrict__ g_l,
                                              float* __restrict__ g_r,
                                              unsigned* __restrict__ adjbit,
                                              int* __restrict__ masks,
                                              float* __restrict__ pmin_f,
                                              float* __restrict__ pmax_f){
  int bx = blockIdx.x, t = threadIdx.x;
  if(bx < 512){
    const float* __restrict__ W = (bx >= 256) ? W_r : W_l;
    float* __restrict__ g = (bx >= 256) ? g_r : g_l;
    int i0 = (bx & 255)*4;
    float acc[4] = {0.f,0.f,0.f,0.f};
#pragma unroll 8
    for(int k=0;k<256;k++){
      float w = W[(size_t)k*256 + t];
#pragma unroll
      for(int r=0;r<4;r++) acc[r] = fmaf(x[(size_t)(i0+r)*256 + k], w, acc[r]);
    }
#pragma unroll
    for(int r=0;r<4;r++) g[(size_t)(i0+r)*256 + t] = acc[r];
  } else if(bx < 1536){
    int i = bx - 512, w = t>>6, lane = t&63;
    if(i < 32) masks[i*256 + t] = 0;
#pragma unroll
    for(int it=0; it<4; it++){
      int j = w*256 + it*64 + lane;
      int v = adj[(size_t)i*N + j];
      unsigned long long mb = __ballot(v > 0);
      if(lane == 0){
        adjbit[i*32 + w*8 + it*2]     = (unsigned)mb;
        adjbit[i*32 + w*8 + it*2 + 1] = (unsigned)(mb >> 32);
      }
    }
  } else {
    int chunk = bx - 1536;
    if(t < 128){
      float lo = FLT_MAX_, hi = -FLT_MAX_;
      int r0 = chunk*64;
      for(int r=0;r<64;r++){
        float v = feats[(size_t)(r0+r)*128 + t];
        lo = fminf(lo,v); hi = fmaxf(hi,v);
      }
      pmin_f[chunk*128+t]=lo; pmax_f[chunk*128+t]=hi;
    }
  }
}

// ---------------- K2: fused compute_e + g_r min/max + nf norms ----------------
__global__ __launch_bounds__(256) void stage2(const float* __restrict__ g_l,
                                              const float* __restrict__ g_r,
                                              const float* __restrict__ attn_w,
                                              const float* __restrict__ feats,
                                              const float* __restrict__ pmin_f, const float* __restrict__ pmax_f,
                                              float* __restrict__ pmin_g, float* __restrict__ pmax_g,
                                              float* __restrict__ nf,
                                              float* __restrict__ e){
  __shared__ __align__(16) float smem[2*64*68 + 128];
  int bx = blockIdx.x, t = threadIdx.x;
  if(bx < 1024){
    float* grs = smem;                 // [64][68]
    float* gls = smem + 64*68;         // [64][68]
    float* aw  = smem + 2*64*68;       // [64]
    float* aw2 = aw + 64;              // [64]
    int h = bx >> 8, i0 = ((bx>>4)&15)*64, j0 = (bx&15)*64;
    if(t < 64){ float w = attn_w[t]; aw[t]=w; aw2[t]=0.2f*w; }
#pragma unroll
    for(int k=0;k<16;k++){
      int idx = t + k*256; int r = idx>>6, f = idx&63;
      grs[r*68+f] = g_r[(size_t)(i0+r)*256 + h*64 + f];
      gls[r*68+f] = g_l[(size_t)(j0+r)*256 + h*64 + f];
    }
    __syncthreads();
    int tj = t&15, ti = t>>4;
    float acc[4][4];
#pragma unroll
    for(int a=0;a<4;a++)
#pragma unroll
      for(int b=0;b<4;b++) acc[a][b]=0.f;
    for(int fc=0; fc<64; fc+=4){
      float4 wv  = *(float4*)&aw[fc];
      float4 wv2 = *(float4*)&aw2[fc];
      float4 ga4[4], gb4[4];
#pragma unroll
      for(int a=0;a<4;a++) ga4[a] = *(float4*)&grs[(ti*4+a)*68+fc];
#pragma unroll
      for(int b=0;b<4;b++) gb4[b] = *(float4*)&gls[(tj+16*b)*68+fc];
#pragma unroll
      for(int a=0;a<4;a++)
#pragma unroll
        for(int b=0;b<4;b++){
          float s0 = ga4[a].x + gb4[b].x;
          float s1 = ga4[a].y + gb4[b].y;
          float s2 = ga4[a].z + gb4[b].z;
          float s3 = ga4[a].w + gb4[b].w;
          acc[a][b] = fmaf(s0, (s0>=0.f)?wv.x:wv2.x, acc[a][b]);
          acc[a][b] = fmaf(s1, (s1>=0.f)?wv.y:wv2.y, acc[a][b]);
          acc[a][b] = fmaf(s2, (s2>=0.f)?wv.z:wv2.z, acc[a][b]);
          acc[a][b] = fmaf(s3, (s3>=0.f)?wv.w:wv2.w, acc[a][b]);
        }
    }
#pragma unroll
    for(int a=0;a<4;a++)
#pragma unroll
      for(int b=0;b<4;b++){
        int i = i0 + ti*4 + a, j = j0 + tj + 16*b;
        e[((size_t)h*N + i)*N + j] = acc[a][b];
      }
  } else if(bx < 1040){
    int chunk = bx - 1024;
    float lo = FLT_MAX_, hi = -FLT_MAX_;
    int r0 = chunk*64;
    for(int r=0;r<64;r++){
      float v = g_r[(size_t)(r0+r)*256 + t];
      lo = fminf(lo,v); hi = fmaxf(hi,v);
    }
    pmin_g[chunk*256+t]=lo; pmax_g[chunk*256+t]=hi;
  } else {
    int i = bx - 1040;
    float* scr = smem;
    float u = 0.f;
    if(t < 128){
      float lo = FLT_MAX_, hi = -FLT_MAX_;
#pragma unroll
      for(int k=0;k<16;k++){
        lo = fminf(lo, pmin_f[k*128+t]);
        hi = fmaxf(hi, pmax_f[k*128+t]);
      }
      float d = hi - lo;
      float v = feats[(size_t)i*128 + t];
      u = (d==0.f) ? 0.f : (v - lo)/d;
    }
    float tot = bred_sum(u*u, scr);
    if(t==0) nf[i] = sqrtf(tot);
  }
}

// ---------------- K3: row stats — wave/(h,row), inline ng, zero barriers ----------
__global__ __launch_bounds__(256) void row_stats(const float* __restrict__ e,
                                                 const unsigned* __restrict__ adjbit,
                                                 const float* __restrict__ nf,
                                                 const float* __restrict__ g_r,
                                                 const float* __restrict__ pmin_g, const float* __restrict__ pmax_g,
                                                 float* __restrict__ ng,
                                                 float* __restrict__ mlA, float* __restrict__ islA,
                                                 float* __restrict__ moA, float* __restrict__ isoA,
                                                 float* __restrict__ maA, float* __restrict__ isaA,
                                                 float* __restrict__ mgA, float* __restrict__ sgA){
  int i = blockIdx.x, t = threadIdx.x, h = t>>6, lane = t&63;
  float glo = FLT_MAX_, ghi = -FLT_MAX_;
#pragma unroll
  for(int k=0;k<16;k++){
    glo = fminf(glo, pmin_g[k*256 + h*64 + lane]);
    ghi = fmaxf(ghi, pmax_g[k*256 + h*64 + lane]);
  }
  float dg = ghi - glo;
  float ug = (g_r[(size_t)i*256 + h*64 + lane] - glo)/dg;   // no guard (matches ref)
  float ngv = sqrtf(bfly_sum(ug*ug));
  if(lane==0) ng[h*N + i] = ngv;

  size_t base = ((size_t)h*N + i)*N;
  float er[16], nfr[16];
  unsigned nib[4];
#pragma unroll
  for(int c=0;c<4;c++){
    float4 e4 = *(const float4*)(e  + base + c*256 + lane*4);
    float4 n4 = *(const float4*)(nf + c*256 + lane*4);
    er[c*4+0]=e4.x; er[c*4+1]=e4.y; er[c*4+2]=e4.z; er[c*4+3]=e4.w;
    nfr[c*4+0]=n4.x; nfr[c*4+1]=n4.y; nfr[c*4+2]=n4.z; nfr[c*4+3]=n4.w;
    nib[c] = (adjbit[i*32 + c*8 + (lane>>3)] >> ((lane&7)*4)) & 0xFu;
  }
  float ml=-FLT_MAX_, mo=-FLT_MAX_, ma=-FLT_MAX_;
#pragma unroll
  for(int c=0;c<4;c++)
#pragma unroll
    for(int k=0;k<4;k++){
      int q = c*4+k;
      float ev = er[q];
      mo = fmaxf(mo, ev);
      if((nib[c]>>k)&1) ml = fmaxf(ml, ev);
      ma = fmaxf(ma, fabsf(nfr[q]-ngv));
    }
  ml = bfly_max(ml); mo = bfly_max(mo); ma = bfly_max(ma);
  float sl=0.f, so=0.f, sa=0.f;
#pragma unroll
  for(int c=0;c<4;c++)
#pragma unroll
    for(int k=0;k<4;k++){
      int q = c*4+k;
      float ev = er[q];
      so += __expf(ev-mo);
      if((nib[c]>>k)&1) sl += __expf(ev-ml);
      sa += __expf(fabsf(nfr[q]-ngv)-ma);
    }
  sl = bfly_sum(sl); so = bfly_sum(so); sa = bfly_sum(sa);
  float isl = 1.f/sl, iso = 1.f/so, isa = 1.f/sa;
  float gg[16];
  float mg = -FLT_MAX_;
#pragma unroll
  for(int q=0;q<16;q++){
    float ev = er[q];
    float omega = __expf(ev-mo)*iso;
    float alpha = __expf(fabsf(nfr[q]-ngv)-ma)*isa;
    float g = 0.5f*(omega + 1.f - alpha);
    gg[q] = g;
    mg = fmaxf(mg, g);
  }
  mg = bfly_max(mg);
  float sg = 0.f;
#pragma unroll
  for(int q=0;q<16;q++) sg += __expf((gg[q]-mg)/1e-3f);
  sg = bfly_sum(sg);
  if(lane==0){
    mlA[h*N+i]=ml; islA[h*N+i]=isl;
    moA[h*N+i]=mo; isoA[h*N+i]=iso;
    maA[h*N+i]=ma; isaA[h*N+i]=isa;
    mgA[h*N+i]=mg; sgA[h*N+i]=sg;
  }
}

// ---------------- K4: applyT — elementwise a_1nd/gamma + transpose ----------------
__global__ __launch_bounds__(256) void applyT(float* __restrict__ e,
                                              float* __restrict__ gamT,
                                              const unsigned* __restrict__ adjbit,
                                              const float* __restrict__ nf,
                                              const float* __restrict__ mlA, const float* __restrict__ islA,
                                              const float* __restrict__ moA, const float* __restrict__ isoA,
                                              const float* __restrict__ maA, const float* __restrict__ isaA,
                                              const float* __restrict__ ng){
  __shared__ __align__(16) float buf1[64][65];
  __shared__ __align__(16) float buf2[64][65];
  __shared__ __align__(16) float buf3[64][65];
  __shared__ float rml[64], risl[64], rmo[64], riso[64], rma[64], risa[64], rng[64], nfs[64];
  int h = blockIdx.y;
  int pp = blockIdx.x; int a = 0;
  while(pp >= 16 - a){ pp -= 16 - a; a++; }
  int b = a + pp;                 // a <= b
  int t = threadIdx.x;
  int rg = t >> 4, c4 = t & 15;

  int i0 = a*64, j0 = b*64;
  if(t < 64){
    int o = h*N + i0 + t;
    rml[t]=mlA[o]; risl[t]=islA[o]; rmo[t]=moA[o]; riso[t]=isoA[o];
    rma[t]=maA[o]; risa[t]=isaA[o]; rng[t]=ng[o]; nfs[t]=nf[j0+t];
  }
  __syncthreads();
  float4 ev[4]; unsigned nb[4];
#pragma unroll
  for(int k=0;k<4;k++){
    int row = rg*4+k;
    ev[k] = *(const float4*)(e + ((size_t)h*N + i0+row)*N + j0 + c4*4);
    nb[k] = (adjbit[(size_t)(i0+row)*32 + (j0>>5) + (c4>>3)] >> ((c4&7)*4)) & 0xFu;
  }
#pragma unroll
  for(int k=0;k<4;k++){
    int row = rg*4+k;
    float ml=rml[row], isl=risl[row], mo=rmo[row], iso=riso[row];
    float ma=rma[row], isa=risa[row], ngv=rng[row];
    float evc[4] = {ev[k].x,ev[k].y,ev[k].z,ev[k].w};
#pragma unroll
    for(int c=0;c<4;c++){
      int j = c4*4+c;
      buf2[j][row] = ((nb[k]>>c)&1) ? __expf(evc[c]-ml)*isl : 0.f;
      float omega = __expf(evc[c]-mo)*iso;
      float alpha = __expf(fabsf(nfs[j]-ngv)-ma)*isa;
      buf1[j][row] = 0.5f*(omega + 1.f - alpha);
    }
  }
  __syncthreads();
#pragma unroll
  for(int k=0;k<4;k++){
    int jr = rg*4+k;
    *(float4*)(gamT + ((size_t)h*N + j0+jr)*N + i0 + c4*4) = *(float4*)&buf1[jr][c4*4];
  }
  if(a == b){
#pragma unroll
    for(int k=0;k<4;k++){
      int jr = rg*4+k;
      *(float4*)(e + ((size_t)h*N + j0+jr)*N + i0 + c4*4) = *(float4*)&buf2[jr][c4*4];
    }
    return;
  }
  int i1 = b*64, j1 = a*64;
  __syncthreads();
  if(t < 64){
    int o = h*N + i1 + t;
    rml[t]=mlA[o]; risl[t]=islA[o]; rmo[t]=moA[o]; riso[t]=isoA[o];
    rma[t]=maA[o]; risa[t]=isaA[o]; rng[t]=ng[o]; nfs[t]=nf[j1+t];
  }
#pragma unroll
  for(int k=0;k<4;k++){
    int row = rg*4+k;
    ev[k] = *(const float4*)(e + ((size_t)h*N + i1+row)*N + j1 + c4*4);
    nb[k] = (adjbit[(size_t)(i1+row)*32 + (j1>>5) + (c4>>3)] >> ((c4&7)*4)) & 0xFu;
  }
  __syncthreads();
#pragma unroll
  for(int k=0;k<4;k++){
    int jr = rg*4+k;
    *(float4*)(e + ((size_t)h*N + i1+jr)*N + j1 + c4*4) = *(float4*)&buf2[jr][c4*4];
  }
#pragma unroll
  for(int k=0;k<4;k++){
    int row = rg*4+k;
    float ml=rml[row], isl=risl[row], mo=rmo[row], iso=riso[row];
    float ma=rma[row], isa=risa[row], ngv=rng[row];
    float evc[4] = {ev[k].x,ev[k].y,ev[k].z,ev[k].w};
#pragma unroll
    for(int c=0;c<4;c++){
      int j = c4*4+c;
      buf3[j][row] = ((nb[k]>>c)&1) ? __expf(evc[c]-ml)*isl : 0.f;
      float omega = __expf(evc[c]-mo)*iso;
      float alpha = __expf(fabsf(nfs[j]-ngv)-ma)*isa;
      buf1[j][row] = 0.5f*(omega + 1.f - alpha);
    }
  }
  __syncthreads();
#pragma unroll
  for(int k=0;k<4;k++){
    int jr = rg*4+k;
    *(float4*)(gamT + ((size_t)h*N + j1+jr)*N + i1 + c4*4) = *(float4*)&buf1[jr][c4*4];
    *(float4*)(e    + ((size_t)h*N + j1+jr)*N + i1 + c4*4) = *(float4*)&buf3[jr][c4*4];
  }
}

// ---------------- K5: top-512 select — wave/column + zero fast path ----------------
__global__ __launch_bounds__(256) void colselect6(const float* __restrict__ a1T,
                                                  const float* __restrict__ gaT,
                                                  int* __restrict__ mask_l,
                                                  int* __restrict__ mask_g){
  __shared__ __align__(16) int hist[4][256];
  int t = threadIdx.x, w = t>>6, lane = t&63;
  int gcol = blockIdx.x*4 + w;            // 0..8191
  int z  = gcol >> 12;                    // 0: a1T, 1: gaT
  int hj = gcol & 4095;                   // h*N + j
  int h  = hj >> 10;
  const float* __restrict__ src = (z ? gaT : a1T) + (size_t)hj * (size_t)N;
  int* __restrict__ mask = z ? mask_g : mask_l;
  int* hw = hist[w];

  unsigned ur[16];
#pragma unroll
  for(int c=0;c<4;c++){
    uint4 u4 = ((const uint4*)src)[c*64 + lane];   // idx = c*256 + lane*4 + k
    ur[c*4+0]=u4.x; ur[c*4+1]=u4.y; ur[c*4+2]=u4.z; ur[c*4+3]=u4.w;
  }
  int np = 0;
#pragma unroll
  for(int q=0;q<16;q++) np += (ur[q] != 0u) ? 1 : 0;
  int cnt_pos = bfly_sumi(np);

  unsigned T; int tneed; int tiecnt = -1;
  if(cnt_pos < KSEL){
    T = 0u; tneed = KSEL - cnt_pos;       // threshold exactly 0; zeros fill by index
  } else {
    unsigned prefix = 0; int kth = KSEL;
#pragma unroll
    for(int b=3;b>=0;b--){
      *(int4*)&hw[lane*4] = make_int4(0,0,0,0);
#pragma unroll
      for(int q=0;q<16;q++){
        unsigned u = ur[q];
        bool act = (b==3) || ((u >> (8*(b+1))) == prefix);
        if(act){
          int bucket = (u >> (8*b)) & 0xFF;
          unsigned long long mball = __ballot(true);
          int lead = __ffsll(mball) - 1;
          int maj = __shfl(bucket, lead, 64);
          if(bucket == maj){
            int cnt = (int)__popcll(__ballot(true));
            if(lane == lead) atomicAdd(&hw[maj], cnt);
          } else {
            atomicAdd(&hw[bucket], 1);
          }
        }
      }
      int4 hv = *(int4*)&hw[lane*4];      // lane owns bins 4l..4l+3
      int s = hv.x+hv.y+hv.z+hv.w;
      int P = s;
#pragma unroll
      for(int off=1; off<64; off<<=1){
        int q2 = __shfl_up(P, off, 64);
        if(lane >= off) P += q2;
      }
      int total = __shfl(P, 63, 64);
      int suffChunk  = total - (P - s);
      int suffChunkN = total - P;
      bool cross = (suffChunk >= kth) && (suffChunkN < kth);
      int selb=0, newk=0, tcnt=0;
      if(cross){
        int s3 = suffChunkN + hv.w;
        int s2 = s3 + hv.z;
        int s1 = s2 + hv.y;
        if(s3 >= kth){ selb=4*lane+3; newk = kth - suffChunkN; tcnt=hv.w; }
        else if(s2 >= kth){ selb=4*lane+2; newk = kth - s3; tcnt=hv.z; }
        else if(s1 >= kth){ selb=4*lane+1; newk = kth - s2; tcnt=hv.y; }
        else { selb=4*lane; newk = kth - s1; tcnt=hv.x; }
      }
      unsigned long long cm = __ballot(cross);
      int csrc = __ffsll(cm) - 1;
      selb   = __shfl(selb, csrc, 64);
      kth    = __shfl(newk, csrc, 64);
      tiecnt = __shfl(tcnt, csrc, 64);
      prefix = (prefix << 8) | (unsigned)selb;
    }
    T = prefix; tneed = kth;
  }

  if(tiecnt == tneed){
#pragma unroll
    for(int c=0;c<4;c++)
#pragma unroll
      for(int k2=0;k2<4;k2++){
        int i = c*256 + lane*4 + k2;
        if(ur[c*4+k2] >= T) mask[h*N + i] = 1;
      }
  } else {
    int base = 0;
#pragma unroll
    for(int c=0;c<4;c++){
      int tc=0;
#pragma unroll
      for(int k2=0;k2<4;k2++) tc += (ur[c*4+k2]==T)?1:0;
      int pc = tc;
#pragma unroll
      for(int off=1; off<64; off<<=1){
        int q2 = __shfl_up(pc, off, 64);
        if(lane >= off) pc += q2;
      }
      int ctot = __shfl(pc, 63, 64);
      int run = base + pc - tc;
#pragma unroll
      for(int k2=0;k2<4;k2++){
        int i = c*256 + lane*4 + k2;
        unsigned u = ur[c*4+k2];
        bool sel = (u > T) || (u == T && run < tneed);
        run += (u==T)?1:0;
        if(sel) mask[h*N + i] = 1;
      }
      base += ctot;
    }
  }
}

// ---------------- K6: attn matmuls — 64-row i-tiles, b128 LDS reads, dbuf --------
// grid (16, HN, 8): i0 = bx*64, h, j0 = s*128. 4 i's/thread -> b128 av/pv reads.
__global__ __launch_bounds__(256) void attn_mm(const float* __restrict__ a1T,
                                               const float* __restrict__ gaT,
                                               const float* __restrict__ g_r,
                                               const float* __restrict__ mgA,
                                               const float* __restrict__ sgA,
                                               const int* __restrict__ mask_g,
                                               float* __restrict__ partL,
                                               float* __restrict__ partG){
  __shared__ __align__(16) float a_t[2][32][68];
  __shared__ __align__(16) float p_t[2][32][68];
  __shared__ __align__(16) float b_s[2][32][68];
  __shared__ float mgv[64], isgv[64];
  __shared__ int mgf[64];
  int i0 = blockIdx.x*64, h = blockIdx.y, s = blockIdx.z, j0 = s*128;
  int t = threadIdx.x;
  if(t < 64){
    mgv[t]  = mgA[h*N + i0 + t];
    isgv[t] = 1.f / sgA[h*N + i0 + t];
    mgf[t]  = mask_g[h*N + i0 + t];
  }
  int fq = t & 15, iq = t >> 4;
  // staging mapping: unit u in {t, t+256}: ju = u>>4 (j row 0..31), i4u = u&15
  int ju0 = t>>4,        i40 = t&15;
  int ju1 = (t+256)>>4,  i41 = t&15;      // = ju0+16, same i4

  float4 va[2], vg[2], vb[2];
  {
    int jb = j0;
    size_t b0 = ((size_t)h*N + jb + ju0)*N + i0 + i40*4;
    size_t b1 = ((size_t)h*N + jb + ju1)*N + i0 + i41*4;
    va[0] = *(const float4*)(a1T + b0);  va[1] = *(const float4*)(a1T + b1);
    vg[0] = *(const float4*)(gaT + b0);  vg[1] = *(const float4*)(gaT + b1);
    vb[0] = *(const float4*)(g_r + (size_t)(jb+ju0)*256 + h*64 + i40*4);
    vb[1] = *(const float4*)(g_r + (size_t)(jb+ju1)*256 + h*64 + i41*4);
  }
  __syncthreads();   // mgv/isgv/mgf visible
  {
    const float inv = 1.f/1024.f;
#pragma unroll
    for(int k=0;k<2;k++){
      int ju = k ? ju1 : ju0, ii = (k ? i41 : i40)*4;
      *(float4*)&a_t[0][ju][(k?i41:i40)*4] = va[k];
      float4 g4 = vg[k], p4;
      p4.x = mgf[ii+0] ? __expf((g4.x - mgv[ii+0])/1e-3f)*isgv[ii+0] : inv;
      p4.y = mgf[ii+1] ? __expf((g4.y - mgv[ii+1])/1e-3f)*isgv[ii+1] : inv;
      p4.z = mgf[ii+2] ? __expf((g4.z - mgv[ii+2])/1e-3f)*isgv[ii+2] : inv;
      p4.w = mgf[ii+3] ? __expf((g4.w - mgv[ii+3])/1e-3f)*isgv[ii+3] : inv;
      *(float4*)&p_t[0][ju][(k?i41:i40)*4] = p4;
      *(float4*)&b_s[0][ju][(k?i41:i40)*4] = vb[k];
    }
  }
  float4 accL[4], accG[4];
#pragma unroll
  for(int r=0;r<4;r++){ accL[r]=make_float4(0,0,0,0); accG[r]=make_float4(0,0,0,0); }

  for(int sub=0; sub<4; sub++){
    int cur = sub & 1;
    __syncthreads();                       // buf[cur] ready; buf[1-cur] free
    if(sub < 3){                           // prefetch next tile (overlaps compute)
      int jb = j0 + (sub+1)*32;
      size_t b0 = ((size_t)h*N + jb + ju0)*N + i0 + i40*4;
      size_t b1 = ((size_t)h*N + jb + ju1)*N + i0 + i41*4;
      va[0] = *(const float4*)(a1T + b0);  va[1] = *(const float4*)(a1T + b1);
      vg[0] = *(const float4*)(gaT + b0);  vg[1] = *(const float4*)(gaT + b1);
      vb[0] = *(const float4*)(g_r + (size_t)(jb+ju0)*256 + h*64 + i40*4);
      vb[1] = *(const float4*)(g_r + (size_t)(jb+ju1)*256 + h*64 + i41*4);
    }
#pragma unroll 4
    for(int j=0;j<32;j++){
      float4 bv = *(float4*)&b_s[cur][j][fq*4];
      float4 av = *(float4*)&a_t[cur][j][iq*4];
      float4 pv = *(float4*)&p_t[cur][j][iq*4];
      accL[0].x = fmaf(av.x, bv.x, accL[0].x); accL[0].y = fmaf(av.x, bv.y, accL[0].y);
      accL[0].z = fmaf(av.x, bv.z, accL[0].z); accL[0].w = fmaf(av.x, bv.w, accL[0].w);
      accL[1].x = fmaf(av.y, bv.x, accL[1].x); accL[1].y = fmaf(av.y, bv.y, accL[1].y);
      accL[1].z = fmaf(av.y, bv.z, accL[1].z); accL[1].w = fmaf(av.y, bv.w, accL[1].w);
      accL[2].x = fmaf(av.z, bv.x, accL[2].x); accL[2].y = fmaf(av.z, bv.y, accL[2].y);
      accL[2].z = fmaf(av.z, bv.z, accL[2].z); accL[2].w = fmaf(av.z, bv.w, accL[2].w);
      accL[3].x = fmaf(av.w, bv.x, accL[3].x); accL[3].y = fmaf(av.w, bv.y, accL[3].y);
      accL[3].z = fmaf(av.w, bv.z, accL[3].z); accL[3].w = fmaf(av.w, bv.w, accL[3].w);
      accG[0].x = fmaf(pv.x, bv.x, accG[0].x); accG[0].y = fmaf(pv.x, bv.y, accG[0].y);
      accG[0].z = fmaf(pv.x, bv.z, accG[0].z); accG[0].w = fmaf(pv.x, bv.w, accG[0].w);
      accG[1].x = fmaf(pv.y, bv.x, accG[1].x); accG[1].y = fmaf(pv.y, bv.y, accG[1].y);
      accG[1].z = fmaf(pv.y, bv.z, accG[1].z); accG[1].w = fmaf(pv.y, bv.w, accG[1].w);
      accG[2].x = fmaf(pv.z, bv.x, accG[2].x); accG[2].y = fmaf(pv.z, bv.y, accG[2].y);
      accG[2].z = fmaf(pv.z, bv.z, accG[2].z); accG[2].w = fmaf(pv.z, bv.w, accG[2].w);
      accG[3].x = fmaf(pv.w, bv.x, accG[3].x); accG[3].y = fmaf(pv.w, bv.y, accG[3].y);
      accG[3].z = fmaf(pv.w, bv.z, accG[3].z); accG[3].w = fmaf(pv.w, bv.w, accG[3].w);
    }
    if(sub < 3){                           // write next buffer
      int nxt = 1 - cur;
      const float inv = 1.f/1024.f;
#pragma unroll
      for(int k=0;k<2;k++){
        int ju = k ? ju1 : ju0, ii = (k ? i41 : i40)*4;
        *(float4*)&a_t[nxt][ju][(k?i41:i40)*4] = va[k];
        float4 g4 = vg[k], p4;
        p4.x = mgf[ii+0] ? __expf((g4.x - mgv[ii+0])/1e-3f)*isgv[ii+0] : inv;
        p4.y = mgf[ii+1] ? __expf((g4.y - mgv[ii+1])/1e-3f)*isgv[ii+1] : inv;
        p4.z = mgf[ii+2] ? __expf((g4.z - mgv[ii+2])/1e-3f)*isgv[ii+2] : inv;
        p4.w = mgf[ii+3] ? __expf((g4.w - mgv[ii+3])/1e-3f)*isgv[ii+3] : inv;
        *(float4*)&p_t[nxt][ju][(k?i41:i40)*4] = p4;
        *(float4*)&b_s[nxt][ju][(k?i41:i40)*4] = vb[k];
      }
    }
  }
#pragma unroll
  for(int r=0;r<4;r++){
    int i = i0 + iq*4 + r;
    size_t o = ((size_t)s*N + i)*256 + h*64 + fq*4;
    *(float4*)&partL[o] = accL[r];
    *(float4*)&partG[o] = accG[r];
  }
}

// ---------------- K7: reduce partials + delta-gate epilogue ----------------
__global__ __launch_bounds__(256) void epilogue(const float* __restrict__ partL,
                                                const float* __restrict__ partG,
                                                const int* __restrict__ mask_l,
                                                const float* __restrict__ W_delta,
                                                const float* __restrict__ b_delta,
                                                float* __restrict__ out){
  __shared__ float cat[4][128];
  __shared__ float inter_s[4][64];
  int i = blockIdx.x, t = threadIdx.x;
  int h = t>>6, f = t&63;
  float sl = 0.f, sg = 0.f;
#pragma unroll
  for(int s2=0;s2<8;s2++){
    size_t o = ((size_t)s2*N + i)*256 + h*64 + f;
    sl += partL[o];
    sg += partG[o];
  }
  if(!mask_l[h*N + i]) sl = 0.f;
  cat[h][f]      = sl;
  cat[h][64 + f] = sg;
  __syncthreads();
  float d = b_delta[f];
  for(int c=0;c<128;c++) d = fmaf(cat[h][c], W_delta[(size_t)c*64 + f], d);
  d = (d >= 0.f) ? d : 0.2f*d;
  inter_s[h][f] = d;
  __syncthreads();
  float m = inter_s[0][f];
#pragma unroll
  for(int hh=1;hh<4;hh++) m = fmaxf(m, inter_s[hh][f]);
  float ssum = 0.f;
#pragma unroll
  for(int hh=0;hh<4;hh++) ssum += __expf(inter_s[hh][f]-m);
  float delta = __expf(d - m)/ssum;
  out[(size_t)i*256 + h*64 + f] = delta*sl + (1.f - delta)*sg;
}

// ---------------- launch ----------------
extern "C" void kernel_launch(void* const* d_in, const int* in_sizes, int n_in,
                              void* d_out, int out_size, void* d_ws, size_t ws_size,
                              hipStream_t stream) {
  const float* feats  = (const float*)d_in[0];
  const float* x      = (const float*)d_in[1];
  const int*   adj    = (const int*)  d_in[2];
  const float* W_l    = (const float*)d_in[3];
  const float* W_r    = (const float*)d_in[4];
  const float* attn_w = (const float*)d_in[5];
  const float* W_delta= (const float*)d_in[6];
  const float* b_delta= (const float*)d_in[7];
  float* out = (float*)d_out;

  float* ws = (float*)d_ws;
  size_t off = 0;
  float* g_l   = ws+off; off += (size_t)N*256;
  float* g_r   = ws+off; off += (size_t)N*256;
  float* e     = ws+off; off += (size_t)HN*N*N;      // e -> a1T (in-place transposed)
  float* gam   = ws+off; off += (size_t)HN*N*N;      // gaT (written transposed)
  float* partL = ws+off; off += (size_t)8*N*256;     // per-s partials
  float* partG = ws+off; off += (size_t)8*N*256;
  float* pmin_f= ws+off; off += 16*128;
  float* pmax_f= ws+off; off += 16*128;
  float* pmin_g= ws+off; off += 16*256;
  float* pmax_g= ws+off; off += 16*256;
  float* nf    = ws+off; off += N;
  float* ng    = ws+off; off += (size_t)HN*N;
  float* mlA   = ws+off; off += (size_t)HN*N;
  float* islA  = ws+off; off += (size_t)HN*N;
  float* moA   = ws+off; off += (size_t)HN*N;
  float* isoA  = ws+off; off += (size_t)HN*N;
  float* maA   = ws+off; off += (size_t)HN*N;
  float* isaA  = ws+off; off += (size_t)HN*N;
  float* mgA   = ws+off; off += (size_t)HN*N;
  float* sgA   = ws+off; off += (size_t)HN*N;
  int* mask_l  = (int*)(ws+off); off += (size_t)HN*N;   // mask_l & mask_g contiguous
  int* mask_g  = (int*)(ws+off); off += (size_t)HN*N;
  unsigned* adjbit = (unsigned*)(ws+off); off += (size_t)N*32;

  stage1<<<1552, 256, 0, stream>>>(x, W_l, W_r, adj, feats, g_l, g_r, adjbit, mask_l, pmin_f, pmax_f);

  stage2<<<2064, 256, 0, stream>>>(g_l, g_r, attn_w, feats, pmin_f, pmax_f,
                                   pmin_g, pmax_g, nf, e);

  row_stats<<<N, 256, 0, stream>>>(e, adjbit, nf, g_r, pmin_g, pmax_g, ng,
                                   mlA, islA, moA, isoA, maA, isaA, mgA, sgA);

  applyT<<<dim3(136,HN), 256, 0, stream>>>(e, gam, adjbit, nf, mlA, islA, moA, isoA, maA, isaA, ng);

  colselect6<<<2048, 256, 0, stream>>>(e, gam, mask_l, mask_g);

  attn_mm<<<dim3(16,HN,8), 256, 0, stream>>>(e, gam, g_r, mgA, sgA, mask_g, partL, partG);

  epilogue<<<N, 256, 0, stream>>>(partL, partG, mask_l, W_delta, b_delta, out);
}

// Round 14
// 193.038 us; speedup vs baseline: 1.0158x; 1.0158x over previous
//
#include <hip/hip_runtime.h>
#include <cstdint>
#include <cstddef>

#define N 1024
#define HN 4
#define FDIM 64
#define KSEL 512
#define FLT_MAX_ 3.402823466e+38f

// ---------------- reduction helpers ----------------
__device__ __forceinline__ float wred_sum(float v){
#pragma unroll
  for(int o=32;o>0;o>>=1) v += __shfl_down(v,o,64);
  return v;
}
__device__ __forceinline__ float bfly_sum(float v){
#pragma unroll
  for(int o=1;o<64;o<<=1) v += __shfl_xor(v,o,64);
  return v;
}
__device__ __forceinline__ float bfly_max(float v){
#pragma unroll
  for(int o=1;o<64;o<<=1) v = fmaxf(v,__shfl_xor(v,o,64));
  return v;
}
__device__ __forceinline__ int bfly_sumi(int v){
#pragma unroll
  for(int o=1;o<64;o<<=1) v += __shfl_xor(v,o,64);
  return v;
}
__device__ __forceinline__ float bred_sum(float v, float* scr){
  int t=threadIdx.x;
  v = wred_sum(v);
  __syncthreads();
  if((t&63)==0) scr[t>>6]=v;
  __syncthreads();
  return (scr[0]+scr[1])+(scr[2]+scr[3]);
}

// ---------------- K1: fused gemm + pack_adj + mask zero + feats min/max ----------
__global__ __launch_bounds__(256) void stage1(const float* __restrict__ x,
                                              const float* __restrict__ W_l,
                                              const float* __restrict__ W_r,
                                              const int* __restrict__ adj,
                                              const float* __restrict__ feats,
                                              float* __restrict__ g_l,
                                              float* __restrict__ g_r,
                                              unsigned* __restrict__ adjbit,
                                              int* __restrict__ masks,
                                              float* __restrict__ pmin_f,
                                              float* __restrict__ pmax_f){
  int bx = blockIdx.x, t = threadIdx.x;
  if(bx < 512){
    const float* __restrict__ W = (bx >= 256) ? W_r : W_l;
    float* __restrict__ g = (bx >= 256) ? g_r : g_l;
    int i0 = (bx & 255)*4;
    float acc[4] = {0.f,0.f,0.f,0.f};
#pragma unroll 8
    for(int k=0;k<256;k++){
      float w = W[(size_t)k*256 + t];
#pragma unroll
      for(int r=0;r<4;r++) acc[r] = fmaf(x[(size_t)(i0+r)*256 + k], w, acc[r]);
    }
#pragma unroll
    for(int r=0;r<4;r++) g[(size_t)(i0+r)*256 + t] = acc[r];
  } else if(bx < 1536){
    int i = bx - 512, w = t>>6, lane = t&63;
    if(i < 32) masks[i*256 + t] = 0;
#pragma unroll
    for(int it=0; it<4; it++){
      int j = w*256 + it*64 + lane;
      int v = adj[(size_t)i*N + j];
      unsigned long long mb = __ballot(v > 0);
      if(lane == 0){
        adjbit[i*32 + w*8 + it*2]     = (unsigned)mb;
        adjbit[i*32 + w*8 + it*2 + 1] = (unsigned)(mb >> 32);
      }
    }
  } else {
    int chunk = bx - 1536;
    if(t < 128){
      float lo = FLT_MAX_, hi = -FLT_MAX_;
      int r0 = chunk*64;
      for(int r=0;r<64;r++){
        float v = feats[(size_t)(r0+r)*128 + t];
        lo = fminf(lo,v); hi = fmaxf(hi,v);
      }
      pmin_f[chunk*128+t]=lo; pmax_f[chunk*128+t]=hi;
    }
  }
}

// ---------------- K2: fused compute_e + g_r min/max + nf norms ----------------
__global__ __launch_bounds__(256) void stage2(const float* __restrict__ g_l,
                                              const float* __restrict__ g_r,
                                              const float* __restrict__ attn_w,
                                              const float* __restrict__ feats,
                                              const float* __restrict__ pmin_f, const float* __restrict__ pmax_f,
                                              float* __restrict__ pmin_g, float* __restrict__ pmax_g,
                                              float* __restrict__ nf,
                                              float* __restrict__ e){
  __shared__ __align__(16) float smem[2*64*68 + 128];
  int bx = blockIdx.x, t = threadIdx.x;
  if(bx < 1024){
    float* grs = smem;                 // [64][68]
    float* gls = smem + 64*68;         // [64][68]
    float* aw  = smem + 2*64*68;       // [64]
    float* aw2 = aw + 64;              // [64]
    int h = bx >> 8, i0 = ((bx>>4)&15)*64, j0 = (bx&15)*64;
    if(t < 64){ float w = attn_w[t]; aw[t]=w; aw2[t]=0.2f*w; }
#pragma unroll
    for(int k=0;k<16;k++){
      int idx = t + k*256; int r = idx>>6, f = idx&63;
      grs[r*68+f] = g_r[(size_t)(i0+r)*256 + h*64 + f];
      gls[r*68+f] = g_l[(size_t)(j0+r)*256 + h*64 + f];
    }
    __syncthreads();
    int tj = t&15, ti = t>>4;
    float acc[4][4];
#pragma unroll
    for(int a=0;a<4;a++)
#pragma unroll
      for(int b=0;b<4;b++) acc[a][b]=0.f;
    for(int fc=0; fc<64; fc+=4){
      float4 wv  = *(float4*)&aw[fc];
      float4 wv2 = *(float4*)&aw2[fc];
      float4 ga4[4], gb4[4];
#pragma unroll
      for(int a=0;a<4;a++) ga4[a] = *(float4*)&grs[(ti*4+a)*68+fc];
#pragma unroll
      for(int b=0;b<4;b++) gb4[b] = *(float4*)&gls[(tj+16*b)*68+fc];
#pragma unroll
      for(int a=0;a<4;a++)
#pragma unroll
        for(int b=0;b<4;b++){
          float s0 = ga4[a].x + gb4[b].x;
          float s1 = ga4[a].y + gb4[b].y;
          float s2 = ga4[a].z + gb4[b].z;
          float s3 = ga4[a].w + gb4[b].w;
          acc[a][b] = fmaf(s0, (s0>=0.f)?wv.x:wv2.x, acc[a][b]);
          acc[a][b] = fmaf(s1, (s1>=0.f)?wv.y:wv2.y, acc[a][b]);
          acc[a][b] = fmaf(s2, (s2>=0.f)?wv.z:wv2.z, acc[a][b]);
          acc[a][b] = fmaf(s3, (s3>=0.f)?wv.w:wv2.w, acc[a][b]);
        }
    }
#pragma unroll
    for(int a=0;a<4;a++)
#pragma unroll
      for(int b=0;b<4;b++){
        int i = i0 + ti*4 + a, j = j0 + tj + 16*b;
        e[((size_t)h*N + i)*N + j] = acc[a][b];
      }
  } else if(bx < 1040){
    int chunk = bx - 1024;
    float lo = FLT_MAX_, hi = -FLT_MAX_;
    int r0 = chunk*64;
    for(int r=0;r<64;r++){
      float v = g_r[(size_t)(r0+r)*256 + t];
      lo = fminf(lo,v); hi = fmaxf(hi,v);
    }
    pmin_g[chunk*256+t]=lo; pmax_g[chunk*256+t]=hi;
  } else {
    int i = bx - 1040;
    float* scr = smem;
    float u = 0.f;
    if(t < 128){
      float lo = FLT_MAX_, hi = -FLT_MAX_;
#pragma unroll
      for(int k=0;k<16;k++){
        lo = fminf(lo, pmin_f[k*128+t]);
        hi = fmaxf(hi, pmax_f[k*128+t]);
      }
      float d = hi - lo;
      float v = feats[(size_t)i*128 + t];
      u = (d==0.f) ? 0.f : (v - lo)/d;
    }
    float tot = bred_sum(u*u, scr);
    if(t==0) nf[i] = sqrtf(tot);
  }
}

// ---------------- K3: row stats — wave/(h,row), inline ng, zero barriers ----------
__global__ __launch_bounds__(256) void row_stats(const float* __restrict__ e,
                                                 const unsigned* __restrict__ adjbit,
                                                 const float* __restrict__ nf,
                                                 const float* __restrict__ g_r,
                                                 const float* __restrict__ pmin_g, const float* __restrict__ pmax_g,
                                                 float* __restrict__ ng,
                                                 float* __restrict__ mlA, float* __restrict__ islA,
                                                 float* __restrict__ moA, float* __restrict__ isoA,
                                                 float* __restrict__ maA, float* __restrict__ isaA,
                                                 float* __restrict__ mgA, float* __restrict__ sgA){
  int i = blockIdx.x, t = threadIdx.x, h = t>>6, lane = t&63;
  float glo = FLT_MAX_, ghi = -FLT_MAX_;
#pragma unroll
  for(int k=0;k<16;k++){
    glo = fminf(glo, pmin_g[k*256 + h*64 + lane]);
    ghi = fmaxf(ghi, pmax_g[k*256 + h*64 + lane]);
  }
  float dg = ghi - glo;
  float ug = (g_r[(size_t)i*256 + h*64 + lane] - glo)/dg;   // no guard (matches ref)
  float ngv = sqrtf(bfly_sum(ug*ug));
  if(lane==0) ng[h*N + i] = ngv;

  size_t base = ((size_t)h*N + i)*N;
  float er[16], nfr[16];
  unsigned nib[4];
#pragma unroll
  for(int c=0;c<4;c++){
    float4 e4 = *(const float4*)(e  + base + c*256 + lane*4);
    float4 n4 = *(const float4*)(nf + c*256 + lane*4);
    er[c*4+0]=e4.x; er[c*4+1]=e4.y; er[c*4+2]=e4.z; er[c*4+3]=e4.w;
    nfr[c*4+0]=n4.x; nfr[c*4+1]=n4.y; nfr[c*4+2]=n4.z; nfr[c*4+3]=n4.w;
    nib[c] = (adjbit[i*32 + c*8 + (lane>>3)] >> ((lane&7)*4)) & 0xFu;
  }
  float ml=-FLT_MAX_, mo=-FLT_MAX_, ma=-FLT_MAX_;
#pragma unroll
  for(int c=0;c<4;c++)
#pragma unroll
    for(int k=0;k<4;k++){
      int q = c*4+k;
      float ev = er[q];
      mo = fmaxf(mo, ev);
      if((nib[c]>>k)&1) ml = fmaxf(ml, ev);
      ma = fmaxf(ma, fabsf(nfr[q]-ngv));
    }
  ml = bfly_max(ml); mo = bfly_max(mo); ma = bfly_max(ma);
  float sl=0.f, so=0.f, sa=0.f;
#pragma unroll
  for(int c=0;c<4;c++)
#pragma unroll
    for(int k=0;k<4;k++){
      int q = c*4+k;
      float ev = er[q];
      so += __expf(ev-mo);
      if((nib[c]>>k)&1) sl += __expf(ev-ml);
      sa += __expf(fabsf(nfr[q]-ngv)-ma);
    }
  sl = bfly_sum(sl); so = bfly_sum(so); sa = bfly_sum(sa);
  float isl = 1.f/sl, iso = 1.f/so, isa = 1.f/sa;
  float gg[16];
  float mg = -FLT_MAX_;
#pragma unroll
  for(int q=0;q<16;q++){
    float ev = er[q];
    float omega = __expf(ev-mo)*iso;
    float alpha = __expf(fabsf(nfr[q]-ngv)-ma)*isa;
    float g = 0.5f*(omega + 1.f - alpha);
    gg[q] = g;
    mg = fmaxf(mg, g);
  }
  mg = bfly_max(mg);
  float sg = 0.f;
#pragma unroll
  for(int q=0;q<16;q++) sg += __expf((gg[q]-mg)/1e-3f);
  sg = bfly_sum(sg);
  if(lane==0){
    mlA[h*N+i]=ml; islA[h*N+i]=isl;
    moA[h*N+i]=mo; isoA[h*N+i]=iso;
    maA[h*N+i]=ma; isaA[h*N+i]=isa;
    mgA[h*N+i]=mg; sgA[h*N+i]=sg;
  }
}

// ---------------- K4: applyT — elementwise a_1nd/gamma + transpose ----------------
__global__ __launch_bounds__(256) void applyT(float* __restrict__ e,
                                              float* __restrict__ gamT,
                                              const unsigned* __restrict__ adjbit,
                                              const float* __restrict__ nf,
                                              const float* __restrict__ mlA, const float* __restrict__ islA,
                                              const float* __restrict__ moA, const float* __restrict__ isoA,
                                              const float* __restrict__ maA, const float* __restrict__ isaA,
                                              const float* __restrict__ ng){
  __shared__ __align__(16) float buf1[64][65];
  __shared__ __align__(16) float buf2[64][65];
  __shared__ __align__(16) float buf3[64][65];
  __shared__ float rml[64], risl[64], rmo[64], riso[64], rma[64], risa[64], rng[64], nfs[64];
  int h = blockIdx.y;
  int pp = blockIdx.x; int a = 0;
  while(pp >= 16 - a){ pp -= 16 - a; a++; }
  int b = a + pp;                 // a <= b
  int t = threadIdx.x;
  int rg = t >> 4, c4 = t & 15;

  int i0 = a*64, j0 = b*64;
  if(t < 64){
    int o = h*N + i0 + t;
    rml[t]=mlA[o]; risl[t]=islA[o]; rmo[t]=moA[o]; riso[t]=isoA[o];
    rma[t]=maA[o]; risa[t]=isaA[o]; rng[t]=ng[o]; nfs[t]=nf[j0+t];
  }
  __syncthreads();
  float4 ev[4]; unsigned nb[4];
#pragma unroll
  for(int k=0;k<4;k++){
    int row = rg*4+k;
    ev[k] = *(const float4*)(e + ((size_t)h*N + i0+row)*N + j0 + c4*4);
    nb[k] = (adjbit[(size_t)(i0+row)*32 + (j0>>5) + (c4>>3)] >> ((c4&7)*4)) & 0xFu;
  }
#pragma unroll
  for(int k=0;k<4;k++){
    int row = rg*4+k;
    float ml=rml[row], isl=risl[row], mo=rmo[row], iso=riso[row];
    float ma=rma[row], isa=risa[row], ngv=rng[row];
    float evc[4] = {ev[k].x,ev[k].y,ev[k].z,ev[k].w};
#pragma unroll
    for(int c=0;c<4;c++){
      int j = c4*4+c;
      buf2[j][row] = ((nb[k]>>c)&1) ? __expf(evc[c]-ml)*isl : 0.f;
      float omega = __expf(evc[c]-mo)*iso;
      float alpha = __expf(fabsf(nfs[j]-ngv)-ma)*isa;
      buf1[j][row] = 0.5f*(omega + 1.f - alpha);
    }
  }
  __syncthreads();
#pragma unroll
  for(int k=0;k<4;k++){
    int jr = rg*4+k;
    *(float4*)(gamT + ((size_t)h*N + j0+jr)*N + i0 + c4*4) = *(float4*)&buf1[jr][c4*4];
  }
  if(a == b){
#pragma unroll
    for(int k=0;k<4;k++){
      int jr = rg*4+k;
      *(float4*)(e + ((size_t)h*N + j0+jr)*N + i0 + c4*4) = *(float4*)&buf2[jr][c4*4];
    }
    return;
  }
  int i1 = b*64, j1 = a*64;
  __syncthreads();
  if(t < 64){
    int o = h*N + i1 + t;
    rml[t]=mlA[o]; risl[t]=islA[o]; rmo[t]=moA[o]; riso[t]=isoA[o];
    rma[t]=maA[o]; risa[t]=isaA[o]; rng[t]=ng[o]; nfs[t]=nf[j1+t];
  }
#pragma unroll
  for(int k=0;k<4;k++){
    int row = rg*4+k;
    ev[k] = *(const float4*)(e + ((size_t)h*N + i1+row)*N + j1 + c4*4);
    nb[k] = (adjbit[(size_t)(i1+row)*32 + (j1>>5) + (c4>>3)] >> ((c4&7)*4)) & 0xFu;
  }
  __syncthreads();
#pragma unroll
  for(int k=0;k<4;k++){
    int jr = rg*4+k;
    *(float4*)(e + ((size_t)h*N + i1+jr)*N + j1 + c4*4) = *(float4*)&buf2[jr][c4*4];
  }
#pragma unroll
  for(int k=0;k<4;k++){
    int row = rg*4+k;
    float ml=rml[row], isl=risl[row], mo=rmo[row], iso=riso[row];
    float ma=rma[row], isa=risa[row], ngv=rng[row];
    float evc[4] = {ev[k].x,ev[k].y,ev[k].z,ev[k].w};
#pragma unroll
    for(int c=0;c<4;c++){
      int j = c4*4+c;
      buf3[j][row] = ((nb[k]>>c)&1) ? __expf(evc[c]-ml)*isl : 0.f;
      float omega = __expf(evc[c]-mo)*iso;
      float alpha = __expf(fabsf(nfs[j]-ngv)-ma)*isa;
      buf1[j][row] = 0.5f*(omega + 1.f - alpha);
    }
  }
  __syncthreads();
#pragma unroll
  for(int k=0;k<4;k++){
    int jr = rg*4+k;
    *(float4*)(gamT + ((size_t)h*N + j1+jr)*N + i1 + c4*4) = *(float4*)&buf1[jr][c4*4];
    *(float4*)(e    + ((size_t)h*N + j1+jr)*N + i1 + c4*4) = *(float4*)&buf3[jr][c4*4];
  }
}

// ---------------- K5: top-512 select — wave/column + zero fast path ----------------
__global__ __launch_bounds__(256) void colselect6(const float* __restrict__ a1T,
                                                  const float* __restrict__ gaT,
                                                  int* __restrict__ mask_l,
                                                  int* __restrict__ mask_g){
  __shared__ __align__(16) int hist[4][256];
  int t = threadIdx.x, w = t>>6, lane = t&63;
  int gcol = blockIdx.x*4 + w;            // 0..8191
  int z  = gcol >> 12;                    // 0: a1T, 1: gaT
  int hj = gcol & 4095;                   // h*N + j
  int h  = hj >> 10;
  const float* __restrict__ src = (z ? gaT : a1T) + (size_t)hj * (size_t)N;
  int* __restrict__ mask = z ? mask_g : mask_l;
  int* hw = hist[w];

  unsigned ur[16];
#pragma unroll
  for(int c=0;c<4;c++){
    uint4 u4 = ((const uint4*)src)[c*64 + lane];   // idx = c*256 + lane*4 + k
    ur[c*4+0]=u4.x; ur[c*4+1]=u4.y; ur[c*4+2]=u4.z; ur[c*4+3]=u4.w;
  }
  int np = 0;
#pragma unroll
  for(int q=0;q<16;q++) np += (ur[q] != 0u) ? 1 : 0;
  int cnt_pos = bfly_sumi(np);

  unsigned T; int tneed; int tiecnt = -1;
  if(cnt_pos < KSEL){
    T = 0u; tneed = KSEL - cnt_pos;       // threshold exactly 0; zeros fill by index
  } else {
    unsigned prefix = 0; int kth = KSEL;
#pragma unroll
    for(int b=3;b>=0;b--){
      *(int4*)&hw[lane*4] = make_int4(0,0,0,0);
#pragma unroll
      for(int q=0;q<16;q++){
        unsigned u = ur[q];
        bool act = (b==3) || ((u >> (8*(b+1))) == prefix);
        if(act){
          int bucket = (u >> (8*b)) & 0xFF;
          unsigned long long mball = __ballot(true);
          int lead = __ffsll(mball) - 1;
          int maj = __shfl(bucket, lead, 64);
          if(bucket == maj){
            int cnt = (int)__popcll(__ballot(true));
            if(lane == lead) atomicAdd(&hw[maj], cnt);
          } else {
            atomicAdd(&hw[bucket], 1);
          }
        }
      }
      int4 hv = *(int4*)&hw[lane*4];      // lane owns bins 4l..4l+3
      int s = hv.x+hv.y+hv.z+hv.w;
      int P = s;
#pragma unroll
      for(int off=1; off<64; off<<=1){
        int q2 = __shfl_up(P, off, 64);
        if(lane >= off) P += q2;
      }
      int total = __shfl(P, 63, 64);
      int suffChunk  = total - (P - s);
      int suffChunkN = total - P;
      bool cross = (suffChunk >= kth) && (suffChunkN < kth);
      int selb=0, newk=0, tcnt=0;
      if(cross){
        int s3 = suffChunkN + hv.w;
        int s2 = s3 + hv.z;
        int s1 = s2 + hv.y;
        if(s3 >= kth){ selb=4*lane+3; newk = kth - suffChunkN; tcnt=hv.w; }
        else if(s2 >= kth){ selb=4*lane+2; newk = kth - s3; tcnt=hv.z; }
        else if(s1 >= kth){ selb=4*lane+1; newk = kth - s2; tcnt=hv.y; }
        else { selb=4*lane; newk = kth - s1; tcnt=hv.x; }
      }
      unsigned long long cm = __ballot(cross);
      int csrc = __ffsll(cm) - 1;
      selb   = __shfl(selb, csrc, 64);
      kth    = __shfl(newk, csrc, 64);
      tiecnt = __shfl(tcnt, csrc, 64);
      prefix = (prefix << 8) | (unsigned)selb;
    }
    T = prefix; tneed = kth;
  }

  if(tiecnt == tneed){
#pragma unroll
    for(int c=0;c<4;c++)
#pragma unroll
      for(int k2=0;k2<4;k2++){
        int i = c*256 + lane*4 + k2;
        if(ur[c*4+k2] >= T) mask[h*N + i] = 1;
      }
  } else {
    int base = 0;
#pragma unroll
    for(int c=0;c<4;c++){
      int tc=0;
#pragma unroll
      for(int k2=0;k2<4;k2++) tc += (ur[c*4+k2]==T)?1:0;
      int pc = tc;
#pragma unroll
      for(int off=1; off<64; off<<=1){
        int q2 = __shfl_up(pc, off, 64);
        if(lane >= off) pc += q2;
      }
      int ctot = __shfl(pc, 63, 64);
      int run = base + pc - tc;
#pragma unroll
      for(int k2=0;k2<4;k2++){
        int i = c*256 + lane*4 + k2;
        unsigned u = ur[c*4+k2];
        bool sel = (u > T) || (u == T && run < tneed);
        run += (u==T)?1:0;
        if(sel) mask[h*N + i] = 1;
      }
      base += ctot;
    }
  }
}

// ---------------- K6: attn matmuls — double-buffered staging, 32-row tiles (R12) --
// grid (32, HN, 8): i0 = bx*32, h, j0 = s*128. Plain stores to per-s partials.
__global__ __launch_bounds__(256) void attn_mm(const float* __restrict__ a1T,
                                               const float* __restrict__ gaT,
                                               const float* __restrict__ g_r,
                                               const float* __restrict__ mgA,
                                               const float* __restrict__ sgA,
                                               const int* __restrict__ mask_g,
                                               float* __restrict__ partL,
                                               float* __restrict__ partG){
  __shared__ __align__(16) float a_t[2][32][36];
  __shared__ __align__(16) float p_t[2][32][36];
  __shared__ __align__(16) float b_s[2][32][68];
  __shared__ float mgv[32], isgv[32];
  __shared__ int mgf[32];
  int i0 = blockIdx.x*32, h = blockIdx.y, s = blockIdx.z, j0 = s*128;
  int t = threadIdx.x;
  if(t < 32){
    mgv[t]  = mgA[h*N + i0 + t];
    isgv[t] = 1.f / sgA[h*N + i0 + t];
    mgf[t]  = mask_g[h*N + i0 + t];
  }
  int fq = t & 15, iq = t >> 4;
  int jj = t>>3, i4 = t&7, ii = i4*4;
  int jb2a = t>>4, d4a = t&15;
  int idxb = t + 256, jb2b = idxb>>4, d4b = idxb&15;

  float4 va, vg, vb0, vb1;
  // prologue: load sub 0
  {
    int jb = j0;
    size_t base = ((size_t)h*N + jb + jj)*N + i0 + i4*4;
    va  = *(const float4*)(a1T + base);
    vg  = *(const float4*)(gaT + base);
    vb0 = *(const float4*)(g_r + (size_t)(jb+jb2a)*256 + h*64 + d4a*4);
    vb1 = *(const float4*)(g_r + (size_t)(jb+jb2b)*256 + h*64 + d4b*4);
  }
  __syncthreads();   // mgv/isgv/mgf visible
  // write buf 0
  {
    const float inv = 1.f/1024.f;
    *(float4*)&a_t[0][jj][i4*4] = va;
    float4 p4;
    p4.x = mgf[ii+0] ? __expf((vg.x - mgv[ii+0])/1e-3f)*isgv[ii+0] : inv;
    p4.y = mgf[ii+1] ? __expf((vg.y - mgv[ii+1])/1e-3f)*isgv[ii+1] : inv;
    p4.z = mgf[ii+2] ? __expf((vg.z - mgv[ii+2])/1e-3f)*isgv[ii+2] : inv;
    p4.w = mgf[ii+3] ? __expf((vg.w - mgv[ii+3])/1e-3f)*isgv[ii+3] : inv;
    *(float4*)&p_t[0][jj][i4*4] = p4;
    *(float4*)&b_s[0][jb2a][d4a*4] = vb0;
    *(float4*)&b_s[0][jb2b][d4b*4] = vb1;
  }
  float4 accL[2], accG[2];
#pragma unroll
  for(int r=0;r<2;r++){ accL[r]=make_float4(0,0,0,0); accG[r]=make_float4(0,0,0,0); }

  for(int sub=0; sub<4; sub++){
    int cur = sub & 1;
    __syncthreads();                       // buf[cur] ready; buf[1-cur] free
    if(sub < 3){                           // issue next tile's loads (overlap compute)
      int jb = j0 + (sub+1)*32;
      size_t base = ((size_t)h*N + jb + jj)*N + i0 + i4*4;
      va  = *(const float4*)(a1T + base);
      vg  = *(const float4*)(gaT + base);
      vb0 = *(const float4*)(g_r + (size_t)(jb+jb2a)*256 + h*64 + d4a*4);
      vb1 = *(const float4*)(g_r + (size_t)(jb+jb2b)*256 + h*64 + d4b*4);
    }
#pragma unroll 8
    for(int j=0;j<32;j++){
      float4 bv = *(float4*)&b_s[cur][j][fq*4];
      float2 av = *(float2*)&a_t[cur][j][iq*2];
      float2 pv = *(float2*)&p_t[cur][j][iq*2];
      accL[0].x = fmaf(av.x, bv.x, accL[0].x); accL[0].y = fmaf(av.x, bv.y, accL[0].y);
      accL[0].z = fmaf(av.x, bv.z, accL[0].z); accL[0].w = fmaf(av.x, bv.w, accL[0].w);
      accL[1].x = fmaf(av.y, bv.x, accL[1].x); accL[1].y = fmaf(av.y, bv.y, accL[1].y);
      accL[1].z = fmaf(av.y, bv.z, accL[1].z); accL[1].w = fmaf(av.y, bv.w, accL[1].w);
      accG[0].x = fmaf(pv.x, bv.x, accG[0].x); accG[0].y = fmaf(pv.x, bv.y, accG[0].y);
      accG[0].z = fmaf(pv.x, bv.z, accG[0].z); accG[0].w = fmaf(pv.x, bv.w, accG[0].w);
      accG[1].x = fmaf(pv.y, bv.x, accG[1].x); accG[1].y = fmaf(pv.y, bv.y, accG[1].y);
      accG[1].z = fmaf(pv.y, bv.z, accG[1].z); accG[1].w = fmaf(pv.y, bv.w, accG[1].w);
    }
    if(sub < 3){                           // write next buffer (safe: barrier above
      int nxt = 1 - cur;                   //  guaranteed all waves done with it)
      const float inv = 1.f/1024.f;
      *(float4*)&a_t[nxt][jj][i4*4] = va;
      float4 p4;
      p4.x = mgf[ii+0] ? __expf((vg.x - mgv[ii+0])/1e-3f)*isgv[ii+0] : inv;
      p4.y = mgf[ii+1] ? __expf((vg.y - mgv[ii+1])/1e-3f)*isgv[ii+1] : inv;
      p4.z = mgf[ii+2] ? __expf((vg.z - mgv[ii+2])/1e-3f)*isgv[ii+2] : inv;
      p4.w = mgf[ii+3] ? __expf((vg.w - mgv[ii+3])/1e-3f)*isgv[ii+3] : inv;
      *(float4*)&p_t[nxt][jj][i4*4] = p4;
      *(float4*)&b_s[nxt][jb2a][d4a*4] = vb0;
      *(float4*)&b_s[nxt][jb2b][d4b*4] = vb1;
    }
  }
#pragma unroll
  for(int r=0;r<2;r++){
    int i = i0 + iq*2 + r;
    size_t o = ((size_t)s*N + i)*256 + h*64 + fq*4;
    *(float4*)&partL[o] = accL[r];
    *(float4*)&partG[o] = accG[r];
  }
}

// ---------------- K7: reduce partials + delta-gate epilogue ----------------
__global__ __launch_bounds__(256) void epilogue(const float* __restrict__ partL,
                                                const float* __restrict__ partG,
                                                const int* __restrict__ mask_l,
                                                const float* __restrict__ W_delta,
                                                const float* __restrict__ b_delta,
                                                float* __restrict__ out){
  __shared__ float cat[4][128];
  __shared__ float inter_s[4][64];
  int i = blockIdx.x, t = threadIdx.x;
  int h = t>>6, f = t&63;
  float sl = 0.f, sg = 0.f;
#pragma unroll
  for(int s2=0;s2<8;s2++){
    size_t o = ((size_t)s2*N + i)*256 + h*64 + f;
    sl += partL[o];
    sg += partG[o];
  }
  if(!mask_l[h*N + i]) sl = 0.f;
  cat[h][f]      = sl;
  cat[h][64 + f] = sg;
  __syncthreads();
  float d = b_delta[f];
  for(int c=0;c<128;c++) d = fmaf(cat[h][c], W_delta[(size_t)c*64 + f], d);
  d = (d >= 0.f) ? d : 0.2f*d;
  inter_s[h][f] = d;
  __syncthreads();
  float m = inter_s[0][f];
#pragma unroll
  for(int hh=1;hh<4;hh++) m = fmaxf(m, inter_s[hh][f]);
  float ssum = 0.f;
#pragma unroll
  for(int hh=0;hh<4;hh++) ssum += __expf(inter_s[hh][f]-m);
  float delta = __expf(d - m)/ssum;
  out[(size_t)i*256 + h*64 + f] = delta*sl + (1.f - delta)*sg;
}

// ---------------- launch ----------------
extern "C" void kernel_launch(void* const* d_in, const int* in_sizes, int n_in,
                              void* d_out, int out_size, void* d_ws, size_t ws_size,
                              hipStream_t stream) {
  const float* feats  = (const float*)d_in[0];
  const float* x      = (const float*)d_in[1];
  const int*   adj    = (const int*)  d_in[2];
  const float* W_l    = (const float*)d_in[3];
  const float* W_r    = (const float*)d_in[4];
  const float* attn_w = (const float*)d_in[5];
  const float* W_delta= (const float*)d_in[6];
  const float* b_delta= (const float*)d_in[7];
  float* out = (float*)d_out;

  float* ws = (float*)d_ws;
  size_t off = 0;
  float* g_l   = ws+off; off += (size_t)N*256;
  float* g_r   = ws+off; off += (size_t)N*256;
  float* e     = ws+off; off += (size_t)HN*N*N;      // e -> a1T (in-place transposed)
  float* gam   = ws+off; off += (size_t)HN*N*N;      // gaT (written transposed)
  float* partL = ws+off; off += (size_t)8*N*256;     // per-s partials
  float* partG = ws+off; off += (size_t)8*N*256;
  float* pmin_f= ws+off; off += 16*128;
  float* pmax_f= ws+off; off += 16*128;
  float* pmin_g= ws+off; off += 16*256;
  float* pmax_g= ws+off; off += 16*256;
  float* nf    = ws+off; off += N;
  float* ng    = ws+off; off += (size_t)HN*N;
  float* mlA   = ws+off; off += (size_t)HN*N;
  float* islA  = ws+off; off += (size_t)HN*N;
  float* moA   = ws+off; off += (size_t)HN*N;
  float* isoA  = ws+off; off += (size_t)HN*N;
  float* maA   = ws+off; off += (size_t)HN*N;
  float* isaA  = ws+off; off += (size_t)HN*N;
  float* mgA   = ws+off; off += (size_t)HN*N;
  float* sgA   = ws+off; off += (size_t)HN*N;
  int* mask_l  = (int*)(ws+off); off += (size_t)HN*N;   // mask_l & mask_g contiguous
  int* mask_g  = (int*)(ws+off); off += (size_t)HN*N;
  unsigned* adjbit = (unsigned*)(ws+off); off += (size_t)N*32;

  stage1<<<1552, 256, 0, stream>>>(x, W_l, W_r, adj, feats, g_l, g_r, adjbit, mask_l, pmin_f, pmax_f);

  stage2<<<2064, 256, 0, stream>>>(g_l, g_r, attn_w, feats, pmin_f, pmax_f,
                                   pmin_g, pmax_g, nf, e);

  row_stats<<<N, 256, 0, stream>>>(e, adjbit, nf, g_r, pmin_g, pmax_g, ng,
                                   mlA, islA, moA, isoA, maA, isaA, mgA, sgA);

  applyT<<<dim3(136,HN), 256, 0, stream>>>(e, gam, adjbit, nf, mlA, islA, moA, isoA, maA, isaA, ng);

  colselect6<<<2048, 256, 0, stream>>>(e, gam, mask_l, mask_g);

  attn_mm<<<dim3(32,HN,8), 256, 0, stream>>>(e, gam, g_r, mgA, sgA, mask_g, partL, partG);

  epilogue<<<N, 256, 0, stream>>>(partL, partG, mask_l, W_delta, b_delta, out);
}